// Round 3
// baseline (1931.064 us; speedup 1.0000x reference)
//
#include <hip/hip_runtime.h>

#define N_NODES 200000
#define N_EDGES 6400000

// ---------------- fast path: direct L2-atomic pipeline ----------------
//
// Algebra (z_i = z0 + S_i * 1vec, S scalar per node):
//   msg_i(e) = a_i.z0[src] + c_i(e)  +  A_i*S[src]  +  q_i.z0[dst] + B_i*S[dst]
//   agg_i[d] = M_i[d] + A_i*GS[d] + indeg[d]*(q_i.z0[d] + B_i*S[d])
// where M_i[d] = sum_e (a_i.z0[src]+c_i(e))  and indeg are layer-independent
// (one edge pass, eagg), and GS[d] = sum_e S[src] is the only per-layer
// edge work (sagg). All scatter-adds are fire-and-forget global_atomic_add
// (device-scope HW f32 atomics in L2; uniform-random dst => no hotspot).

// zero the atomic accumulators (head of every launch => graph-replay safe)
__global__ __launch_bounds__(256) void zinit_kernel(
    float* __restrict__ M0, float* __restrict__ M1, float* __restrict__ M2,
    int* __restrict__ cnt, float* __restrict__ GS0, float* __restrict__ GS1)
{
    int n = blockIdx.x * 256 + threadIdx.x;
    if (n < N_NODES) {
        M0[n] = 0.0f; M1[n] = 0.0f; M2[n] = 0.0f;
        cnt[n] = 0;  GS0[n] = 0.0f; GS1[n] = 0.0f;
    }
}

// one streaming pass over all edges: M0,M1,M2,indeg via global atomics
__global__ __launch_bounds__(256) void eagg_kernel(
    const int* __restrict__ src, const int* __restrict__ dst,
    const float* __restrict__ r, const float* __restrict__ r_hat,
    const float4* __restrict__ z0, const float* __restrict__ W,
    const float* __restrict__ b,
    float* __restrict__ M0, float* __restrict__ M1, float* __restrict__ M2,
    int* __restrict__ cnt)
{
    int e = blockIdx.x * 256 + threadIdx.x;
    if (e >= N_EDGES) return;
    int s = src[e], d = dst[e];
    float4 zs = z0[s];                      // random gather, L2-resident (3.2MB)
    float rv = r[e];
    size_t he = 3 * (size_t)e;
    float h0 = r_hat[he], h1 = r_hat[he + 1], h2 = r_hat[he + 2];

    float v0 = W[0]  * zs.x + W[1]  * zs.y + W[2]  * zs.z + W[3]  * zs.w
             + W[8]  * rv + W[9]  * h0 + W[10] * h1 + W[11] * h2 + b[0];
    float v1 = W[12] * zs.x + W[13] * zs.y + W[14] * zs.z + W[15] * zs.w
             + W[20] * rv + W[21] * h0 + W[22] * h1 + W[23] * h2 + b[1];
    float v2 = W[24] * zs.x + W[25] * zs.y + W[26] * zs.z + W[27] * zs.w
             + W[32] * rv + W[33] * h0 + W[34] * h1 + W[35] * h2 + b[2];

    unsafeAtomicAdd(&M0[d], v0);            // global_atomic_add_f32, no return
    unsafeAtomicAdd(&M1[d], v1);
    unsafeAtomicAdd(&M2[d], v2);
    atomicAdd(&cnt[d], 1);                  // global_atomic_add_u32
}

// S0 = M0 + indeg * (q0 . z0)
__global__ __launch_bounds__(256) void fin0_kernel(
    const float4* __restrict__ z0, const float* __restrict__ M0,
    const int* __restrict__ cnt, const float* __restrict__ W,
    float* __restrict__ S0)
{
    int n = blockIdx.x * 256 + threadIdx.x;
    if (n >= N_NODES) return;
    float4 zv = z0[n];
    float v0 = W[4] * zv.x + W[5] * zv.y + W[6] * zv.z + W[7] * zv.w;
    S0[n] = M0[n] + (float)cnt[n] * v0;
}

// per-layer graph pass: GS[d] += S[src_e]
__global__ __launch_bounds__(256) void sagg_kernel(
    const int* __restrict__ src, const int* __restrict__ dst,
    const float* __restrict__ S, float* __restrict__ GS)
{
    int e = blockIdx.x * 256 + threadIdx.x;
    if (e >= N_EDGES) return;
    unsafeAtomicAdd(&GS[dst[e]], S[src[e]]);
}

// S = Sp + Md + A*GS + cnt*(q.z0 + B*Sp); final layer writes z_out, x_out
__global__ __launch_bounds__(256) void finL_kernel(
    const float4* __restrict__ z0, const float* __restrict__ GS,
    const float* __restrict__ Md, const int* __restrict__ cnt,
    const float* __restrict__ Wl, const float* __restrict__ Sprev,
    int final_layer, float* __restrict__ Sout,
    float4* __restrict__ z_out, float4* __restrict__ x_out)
{
    int n = blockIdx.x * 256 + threadIdx.x;
    if (n >= N_NODES) return;
    float A = Wl[0] + Wl[1] + Wl[2] + Wl[3];
    float B = Wl[4] + Wl[5] + Wl[6] + Wl[7];
    float4 zv = z0[n];
    float vh = Wl[4] * zv.x + Wl[5] * zv.y + Wl[6] * zv.z + Wl[7] * zv.w;
    float Sp = Sprev[n];
    float C  = (float)cnt[n];
    float S  = Sp + Md[n] + A * GS[n] + C * (vh + B * Sp);
    if (!final_layer) {
        Sout[n] = S;
    } else {
        float4 zo = zv;                 // x = original z0
        zv.x += S; zv.y += S; zv.z += S; zv.w += S;
        z_out[n] = zv;
        x_out[n] = zo;
    }
}

// ---------------- fallback (round-2) ----------------

__global__ __launch_bounds__(256) void init_kernel(
    const float4* __restrict__ z_in, float4* __restrict__ z_cur,
    float4* __restrict__ x_out, float* __restrict__ agg)
{
    int n = blockIdx.x * blockDim.x + threadIdx.x;
    if (n < N_NODES) {
        float4 vv = z_in[n];
        z_cur[n] = vv; x_out[n] = vv; agg[n] = 0.0f;
    }
}

__global__ __launch_bounds__(256) void edge_kernel(
    const float* __restrict__ z, const float* __restrict__ r,
    const float* __restrict__ r_hat, const int* __restrict__ src,
    const int* __restrict__ dst, const float* __restrict__ Wl,
    const float* __restrict__ bl, float* __restrict__ agg)
{
    int e = blockIdx.x * blockDim.x + threadIdx.x;
    if (e >= N_EDGES) return;
    float w0 = Wl[0], w1 = Wl[1], w2 = Wl[2], w3 = Wl[3];
    float w4 = Wl[4], w5 = Wl[5], w6 = Wl[6], w7 = Wl[7];
    float w8 = Wl[8], w9 = Wl[9], w10 = Wl[10], w11 = Wl[11];
    float bias = bl[0];
    int s = src[e], d = dst[e];
    float4 zs = ((const float4*)z)[s];
    float4 zd = ((const float4*)z)[d];
    float rv = r[e];
    const float* rh = r_hat + 3 * (size_t)e;
    float msg = w0*zs.x + w1*zs.y + w2*zs.z + w3*zs.w
              + w4*zd.x + w5*zd.y + w6*zd.z + w7*zd.w
              + w8*rv + w9*rh[0] + w10*rh[1] + w11*rh[2] + bias;
    unsafeAtomicAdd(&agg[d], msg);
}

__global__ __launch_bounds__(256) void node_update(float4* __restrict__ z_cur,
                                                   float* __restrict__ agg)
{
    int n = blockIdx.x * blockDim.x + threadIdx.x;
    if (n < N_NODES) {
        float a = agg[n]; float4 vv = z_cur[n];
        vv.x += a; vv.y += a; vv.z += a; vv.w += a;
        z_cur[n] = vv; agg[n] = 0.0f;
    }
}

__global__ __launch_bounds__(256) void final_update(const float4* __restrict__ z_cur,
                                                    const float* __restrict__ agg,
                                                    float4* __restrict__ z_out)
{
    int n = blockIdx.x * blockDim.x + threadIdx.x;
    if (n < N_NODES) {
        float a = agg[n]; float4 vv = z_cur[n];
        vv.x += a; vv.y += a; vv.z += a; vv.w += a;
        z_out[n] = vv;
    }
}

// ---------------- launch ----------------

extern "C" void kernel_launch(void* const* d_in, const int* in_sizes, int n_in,
                              void* d_out, int out_size, void* d_ws, size_t ws_size,
                              hipStream_t stream)
{
    const float* z     = (const float*)d_in[0];
    const float* r     = (const float*)d_in[1];
    const float* r_hat = (const float*)d_in[2];
    const float* W     = (const float*)d_in[3];
    const float* b     = (const float*)d_in[4];
    const int*   src   = (const int*)d_in[5];
    const int*   dst   = (const int*)d_in[6];
    float* out = (float*)d_out;

    char* ws = (char*)d_ws;
    size_t off = 0;
    auto alloc = [&](size_t bytes) {
        void* p = ws + off;
        off += (bytes + 15) & ~(size_t)15;
        return p;
    };
    float* M0  = (float*)alloc((size_t)N_NODES * 4);
    float* M1  = (float*)alloc((size_t)N_NODES * 4);
    float* M2  = (float*)alloc((size_t)N_NODES * 4);
    int*   cnt = (int*)  alloc((size_t)N_NODES * 4);
    float* GS0 = (float*)alloc((size_t)N_NODES * 4);
    float* GS1 = (float*)alloc((size_t)N_NODES * 4);
    float* S0  = (float*)alloc((size_t)N_NODES * 4);
    float* S1  = (float*)alloc((size_t)N_NODES * 4);
    size_t required = off;

    dim3 nblk((N_NODES + 255) / 256);
    dim3 eblk((N_EDGES + 255) / 256);

    if (ws_size >= required) {
        zinit_kernel<<<nblk, 256, 0, stream>>>(M0, M1, M2, cnt, GS0, GS1);
        // layer-independent: M0,M1,M2,indeg in one edge pass
        eagg_kernel<<<eblk, 256, 0, stream>>>(src, dst, r, r_hat,
                                              (const float4*)z, W, b,
                                              M0, M1, M2, cnt);
        fin0_kernel<<<nblk, 256, 0, stream>>>((const float4*)z, M0, cnt, W, S0);
        // layer 1
        sagg_kernel<<<eblk, 256, 0, stream>>>(src, dst, S0, GS0);
        finL_kernel<<<nblk, 256, 0, stream>>>(
            (const float4*)z, GS0, M1, cnt, W + 12, S0, 0,
            S1, (float4*)out, (float4*)(out + 4 * (size_t)N_NODES));
        // layer 2 (writes z_out and x_out)
        sagg_kernel<<<eblk, 256, 0, stream>>>(src, dst, S1, GS1);
        finL_kernel<<<nblk, 256, 0, stream>>>(
            (const float4*)z, GS1, M2, cnt, W + 24, S1, 1,
            S0 /*unused*/, (float4*)out, (float4*)(out + 4 * (size_t)N_NODES));
    } else {
        // fallback: round-2 path
        float* agg   = (float*)d_ws;
        float* z_cur = agg + N_NODES;
        init_kernel<<<nblk, 256, 0, stream>>>(
            (const float4*)z, (float4*)z_cur,
            (float4*)(out + 4 * (size_t)N_NODES), agg);
        for (int i = 0; i < 3; ++i) {
            edge_kernel<<<eblk, 256, 0, stream>>>(
                z_cur, r, r_hat, src, dst, W + 12 * i, b + i, agg);
            if (i < 2)
                node_update<<<nblk, 256, 0, stream>>>((float4*)z_cur, agg);
            else
                final_update<<<nblk, 256, 0, stream>>>(
                    (const float4*)z_cur, agg, (float4*)out);
        }
    }
}

// Round 4
// 373.590 us; speedup vs baseline: 5.1689x; 5.1689x over previous
//
#include <hip/hip_runtime.h>

#define N_NODES 200000
#define N_EDGES 6400000
#define K_BUCKETS 64
#define BUCKET 3125         // 64*3125 = 200000 exactly; dl < 4096 (12 bits)
#define NSB 3200            // chunks
#define CHUNK 2000          // NSB*CHUNK == N_EDGES exactly
#define P_SPLIT 8           // blocks per bucket in aggregation (512 blocks, 1024 thr)

__device__ __forceinline__ unsigned short f2bf(float x) {
    unsigned u = __float_as_uint(x);
    u += 0x7fffu + ((u >> 16) & 1u);      // RNE to bf16
    return (unsigned short)(u >> 16);
}
__device__ __forceinline__ float bf2f(unsigned short h) {
    return __uint_as_float((unsigned)h << 16);
}

// ---------------- fast path ----------------

// x_out = z0 ; u0 = a0.z0 ; v0 = q0.z0   (S0 = 0)
__global__ __launch_bounds__(256) void prep_kernel(
    const float4* __restrict__ z, float4* __restrict__ x_out,
    const float* __restrict__ W,
    float* __restrict__ u, float* __restrict__ v)
{
    int n = blockIdx.x * 256 + threadIdx.x;
    if (n >= N_NODES) return;
    float4 zv = z[n];
    x_out[n] = zv;
    float a0 = W[0], a1 = W[1], a2 = W[2], a3 = W[3];
    float q0 = W[4], q1 = W[5], q2 = W[6], q3 = W[7];
    u[n] = a0 * zv.x + a1 * zv.y + a2 * zv.z + a3 * zv.w;
    v[n] = q0 * zv.x + q1 * zv.y + q2 * zv.z + q3 * zv.w;
}

// per-chunk bucket histogram, layout counts[sb*K + k]  (coalesced store)
__global__ __launch_bounds__(256) void hist_kernel(const int* __restrict__ dst,
                                                   int* __restrict__ counts)
{
    __shared__ int cnt[K_BUCKETS];
    int tid = threadIdx.x, sb = blockIdx.x;
    if (tid < K_BUCKETS) cnt[tid] = 0;
    __syncthreads();
    int e0 = sb * CHUNK;
    for (int i = tid; i < CHUNK; i += 256)
        atomicAdd(&cnt[dst[e0 + i] / BUCKET], 1);
    __syncthreads();
    if (tid < K_BUCKETS) counts[sb * K_BUCKETS + tid] = cnt[tid];
}

// per-bucket exclusive scan across chunks (strided access, small data)
__global__ __launch_bounds__(256) void scan_cols(const int* __restrict__ counts,
                                                 int* __restrict__ baseRel,
                                                 int* __restrict__ tot)
{
    __shared__ int buf[256];
    __shared__ int carry_s;
    int k = blockIdx.x, tid = threadIdx.x;
    if (tid == 0) carry_s = 0;
    __syncthreads();
    for (int base = 0; base < NSB; base += 256) {
        int idx = base + tid;
        int v = (idx < NSB) ? counts[idx * K_BUCKETS + k] : 0;
        buf[tid] = v;
        __syncthreads();
        for (int off = 1; off < 256; off <<= 1) {
            int t = (tid >= off) ? buf[tid - off] : 0;
            __syncthreads();
            buf[tid] += t;
            __syncthreads();
        }
        int incl = buf[tid];
        if (idx < NSB) baseRel[idx * K_BUCKETS + k] = carry_s + incl - v;
        __syncthreads();
        if (tid == 255) carry_s += incl;
        __syncthreads();
    }
    if (tid == 255) tot[k] = carry_s;
}

// scan 64 bucket totals -> bstart[0..64]   (one wave)
__global__ __launch_bounds__(64) void scan_tot(const int* __restrict__ tot,
                                               int* __restrict__ bstart)
{
    __shared__ int buf[K_BUCKETS];
    int tid = threadIdx.x;
    int v = tot[tid];
    buf[tid] = v;
    __syncthreads();
    for (int off = 1; off < K_BUCKETS; off <<= 1) {
        int t = (tid >= off) ? buf[tid - off] : 0;
        __syncthreads();
        buf[tid] += t;
        __syncthreads();
    }
    bstart[tid] = buf[tid] - v;
    if (tid == K_BUCKETS - 1) bstart[K_BUCKETS] = buf[tid];
}

// counting-sort scatter: counts pre-loaded; permutation in LDS; K=64 buckets
// => pass-C runs avg 31 elems (125B packed) -> coalesced global stores.
__global__ __launch_bounds__(256) void scatter_kernel(
    const int* __restrict__ src, const int* __restrict__ dst,
    const float* __restrict__ r, const float* __restrict__ r_hat,
    const float* __restrict__ W, const float* __restrict__ b,
    const int* __restrict__ counts, const int* __restrict__ baseRel,
    const int* __restrict__ bstart,
    int* __restrict__ packedA, unsigned short* __restrict__ c0a,
    unsigned short* __restrict__ c1a, unsigned short* __restrict__ c2a)
{
    __shared__ int cur[K_BUCKETS];
    __shared__ int delta[K_BUCKETS];
    __shared__ int scanbuf[K_BUCKETS];
    __shared__ int            lpack[CHUNK];
    __shared__ unsigned short lc0[CHUNK];
    __shared__ unsigned short lc1[CHUNK];
    __shared__ unsigned short lc2[CHUNK];
    __shared__ unsigned char  skb[CHUNK];

    int tid = threadIdx.x, sb = blockIdx.x;

    // per-chunk per-bucket exclusive scan (64 entries, first wave)
    if (tid < K_BUCKETS) {
        int v = counts[sb * K_BUCKETS + tid];
        scanbuf[tid] = v;
    }
    __syncthreads();
    for (int off = 1; off < K_BUCKETS; off <<= 1) {
        int t = 0;
        if (tid < K_BUCKETS && tid >= off) t = scanbuf[tid - off];
        __syncthreads();
        if (tid < K_BUCKETS) scanbuf[tid] += t;
        __syncthreads();
    }
    if (tid < K_BUCKETS) {
        int v = counts[sb * K_BUCKETS + tid];
        int localBase = scanbuf[tid] - v;
        int gBase = bstart[tid] + baseRel[sb * K_BUCKETS + tid];
        delta[tid] = gBase - localBase;
        cur[tid] = localBase;
    }
    __syncthreads();

    float w8_0 = W[8],  w9_0 = W[9],  w10_0 = W[10], w11_0 = W[11], b0 = b[0];
    float w8_1 = W[20], w9_1 = W[21], w10_1 = W[22], w11_1 = W[23], b1 = b[1];
    float w8_2 = W[32], w9_2 = W[33], w10_2 = W[34], w11_2 = W[35], b2 = b[2];

    int e0 = sb * CHUNK;
    // pass B: coalesced global reads, scattered LDS writes to sorted slot
    for (int i = tid; i < CHUNK; i += 256) {
        int e = e0 + i;
        int d = dst[e];
        int k = d / BUCKET;
        int dl = d - k * BUCKET;
        int slot = atomicAdd(&cur[k], 1);
        int sn = src[e];
        float rv = r[e];
        size_t he = 3 * (size_t)e;
        float h0 = r_hat[he], h1 = r_hat[he + 1], h2 = r_hat[he + 2];
        lpack[slot] = (sn << 12) | dl;
        lc0[slot] = f2bf(w8_0 * rv + w9_0 * h0 + w10_0 * h1 + w11_0 * h2 + b0);
        lc1[slot] = f2bf(w8_1 * rv + w9_1 * h0 + w10_1 * h1 + w11_1 * h2 + b1);
        lc2[slot] = f2bf(w8_2 * rv + w9_2 * h0 + w10_2 * h1 + w11_2 * h2 + b2);
        skb[slot] = (unsigned char)k;
    }
    __syncthreads();

    // pass C: sequential LDS reads, run-coalesced global stores
    for (int s = tid; s < CHUNK; s += 256) {
        int k = skb[s];
        int gpos = delta[k] + s;
        packedA[gpos] = lpack[s];
        c0a[gpos] = lc0[s];
        c1a[gpos] = lc1[s];
        c2a[gpos] = lc2[s];
    }
}

// partial aggregation: P_SPLIT blocks per bucket, 1024 threads (32 waves/CU),
// native ds_add_f32 via unsafeAtomicAdd (plain atomicAdd = LDS CAS loop).
__global__ __launch_bounds__(1024) void pagg_kernel(
    const int* __restrict__ packedA, const unsigned short* __restrict__ ca,
    const int* __restrict__ bstart,
    const float* __restrict__ u, const float* __restrict__ v,
    float* __restrict__ partial)
{
    __shared__ float vsl[BUCKET];
    __shared__ float aggsl[BUCKET];
    int tid = threadIdx.x, blk = blockIdx.x;
    int k = blk / P_SPLIT;
    int p = blk - k * P_SPLIT;
    int nbase = k * BUCKET;           // 64*3125 == 200000: no tail anywhere

    for (int i = tid; i < BUCKET; i += 1024) {
        aggsl[i] = 0.0f;
        vsl[i] = v[nbase + i];
    }
    __syncthreads();

    int estart = bstart[k], eend = bstart[k + 1];
    int len = eend - estart;
    int per = (len + P_SPLIT - 1) / P_SPLIT;
    int lo = estart + p * per;
    int hi = min(lo + per, eend);

    for (int j = lo + tid; j < hi; j += 1024) {
        int pack = packedA[j];
        int s = pack >> 12;
        int dl = pack & 4095;
        float c = bf2f(ca[j]);
        unsafeAtomicAdd(&aggsl[dl], u[s] + vsl[dl] + c);   // ds_add_f32
    }
    __syncthreads();

    float* pout = partial + (size_t)blk * BUCKET;
    for (int i = tid; i < BUCKET; i += 1024) pout[i] = aggsl[i];
}

// finalize layer: S' = S + sum(partials); compute next u,v (or final z)
__global__ __launch_bounds__(256) void fin_kernel(
    const float4* __restrict__ z0, const float* __restrict__ partial,
    const float* __restrict__ Sin, float* __restrict__ Sout,
    const float* __restrict__ W, int layer,
    float* __restrict__ u, float* __restrict__ v, float4* __restrict__ z_out)
{
    int n = blockIdx.x * 256 + threadIdx.x;
    if (n >= N_NODES) return;
    int k = n / BUCKET;
    int i = n - k * BUCKET;
    float agg = 0.0f;
    const float* pk = partial + (size_t)k * P_SPLIT * BUCKET + i;
#pragma unroll
    for (int p = 0; p < P_SPLIT; ++p) agg += pk[(size_t)p * BUCKET];
    float S = ((layer == 0) ? 0.0f : Sin[n]) + agg;
    if (layer < 2) {
        const float* Wn = W + 12 * (layer + 1);
        float a0 = Wn[0], a1 = Wn[1], a2 = Wn[2], a3 = Wn[3];
        float q0 = Wn[4], q1 = Wn[5], q2 = Wn[6], q3 = Wn[7];
        float A = a0 + a1 + a2 + a3, B = q0 + q1 + q2 + q3;
        float4 zv = z0[n];
        Sout[n] = S;
        u[n] = a0 * zv.x + a1 * zv.y + a2 * zv.z + a3 * zv.w + A * S;
        v[n] = q0 * zv.x + q1 * zv.y + q2 * zv.z + q3 * zv.w + B * S;
    } else {
        float4 zv = z0[n];
        zv.x += S; zv.y += S; zv.z += S; zv.w += S;
        z_out[n] = zv;
    }
}

// ---------------- fallback (round-2) ----------------

__global__ __launch_bounds__(256) void init_kernel(
    const float4* __restrict__ z_in, float4* __restrict__ z_cur,
    float4* __restrict__ x_out, float* __restrict__ agg)
{
    int n = blockIdx.x * blockDim.x + threadIdx.x;
    if (n < N_NODES) {
        float4 vv = z_in[n];
        z_cur[n] = vv; x_out[n] = vv; agg[n] = 0.0f;
    }
}

__global__ __launch_bounds__(256) void edge_kernel(
    const float* __restrict__ z, const float* __restrict__ r,
    const float* __restrict__ r_hat, const int* __restrict__ src,
    const int* __restrict__ dst, const float* __restrict__ Wl,
    const float* __restrict__ bl, float* __restrict__ agg)
{
    int e = blockIdx.x * blockDim.x + threadIdx.x;
    if (e >= N_EDGES) return;
    float w0 = Wl[0], w1 = Wl[1], w2 = Wl[2], w3 = Wl[3];
    float w4 = Wl[4], w5 = Wl[5], w6 = Wl[6], w7 = Wl[7];
    float w8 = Wl[8], w9 = Wl[9], w10 = Wl[10], w11 = Wl[11];
    float bias = bl[0];
    int s = src[e], d = dst[e];
    float4 zs = ((const float4*)z)[s];
    float4 zd = ((const float4*)z)[d];
    float rv = r[e];
    const float* rh = r_hat + 3 * (size_t)e;
    float msg = w0*zs.x + w1*zs.y + w2*zs.z + w3*zs.w
              + w4*zd.x + w5*zd.y + w6*zd.z + w7*zd.w
              + w8*rv + w9*rh[0] + w10*rh[1] + w11*rh[2] + bias;
    unsafeAtomicAdd(&agg[d], msg);
}

__global__ __launch_bounds__(256) void node_update(float4* __restrict__ z_cur,
                                                   float* __restrict__ agg)
{
    int n = blockIdx.x * blockDim.x + threadIdx.x;
    if (n < N_NODES) {
        float a = agg[n]; float4 vv = z_cur[n];
        vv.x += a; vv.y += a; vv.z += a; vv.w += a;
        z_cur[n] = vv; agg[n] = 0.0f;
    }
}

__global__ __launch_bounds__(256) void final_update(const float4* __restrict__ z_cur,
                                                    const float* __restrict__ agg,
                                                    float4* __restrict__ z_out)
{
    int n = blockIdx.x * blockDim.x + threadIdx.x;
    if (n < N_NODES) {
        float a = agg[n]; float4 vv = z_cur[n];
        vv.x += a; vv.y += a; vv.z += a; vv.w += a;
        z_out[n] = vv;
    }
}

// ---------------- launch ----------------

extern "C" void kernel_launch(void* const* d_in, const int* in_sizes, int n_in,
                              void* d_out, int out_size, void* d_ws, size_t ws_size,
                              hipStream_t stream)
{
    const float* z     = (const float*)d_in[0];
    const float* r     = (const float*)d_in[1];
    const float* r_hat = (const float*)d_in[2];
    const float* W     = (const float*)d_in[3];
    const float* b     = (const float*)d_in[4];
    const int*   src   = (const int*)d_in[5];
    const int*   dst   = (const int*)d_in[6];
    float* out = (float*)d_out;

    char* ws = (char*)d_ws;
    size_t off = 0;
    auto alloc = [&](size_t bytes) {
        void* p = ws + off;
        off += (bytes + 15) & ~(size_t)15;
        return p;
    };
    int*            packedA = (int*)alloc((size_t)N_EDGES * 4);
    unsigned short* c0a     = (unsigned short*)alloc((size_t)N_EDGES * 2);
    unsigned short* c1a     = (unsigned short*)alloc((size_t)N_EDGES * 2);
    unsigned short* c2a     = (unsigned short*)alloc((size_t)N_EDGES * 2);
    int*            counts  = (int*)alloc((size_t)NSB * K_BUCKETS * 4);
    int*            baseRel = (int*)alloc((size_t)NSB * K_BUCKETS * 4);
    int*            tot     = (int*)alloc((size_t)K_BUCKETS * 4);
    int*            bstart  = (int*)alloc((size_t)(K_BUCKETS + 1) * 4);
    float*          Sa      = (float*)alloc((size_t)N_NODES * 4);
    float*          Sb      = (float*)alloc((size_t)N_NODES * 4);
    float*          ubuf    = (float*)alloc((size_t)N_NODES * 4);
    float*          vbuf    = (float*)alloc((size_t)N_NODES * 4);
    float*          partial = (float*)alloc((size_t)K_BUCKETS * P_SPLIT * BUCKET * 4);
    size_t required = off;

    dim3 nblk((N_NODES + 255) / 256);

    if (ws_size >= required) {
        prep_kernel<<<nblk, 256, 0, stream>>>(
            (const float4*)z, (float4*)(out + 4 * (size_t)N_NODES), W, ubuf, vbuf);
        hist_kernel<<<NSB, 256, 0, stream>>>(dst, counts);
        scan_cols<<<K_BUCKETS, 256, 0, stream>>>(counts, baseRel, tot);
        scan_tot<<<1, 64, 0, stream>>>(tot, bstart);
        scatter_kernel<<<NSB, 256, 0, stream>>>(src, dst, r, r_hat, W, b,
                                                counts, baseRel, bstart,
                                                packedA, c0a, c1a, c2a);
        // layer 0
        pagg_kernel<<<K_BUCKETS * P_SPLIT, 1024, 0, stream>>>(
            packedA, c0a, bstart, ubuf, vbuf, partial);
        fin_kernel<<<nblk, 256, 0, stream>>>(
            (const float4*)z, partial, Sa, Sa, W, 0, ubuf, vbuf, (float4*)out);
        // layer 1
        pagg_kernel<<<K_BUCKETS * P_SPLIT, 1024, 0, stream>>>(
            packedA, c1a, bstart, ubuf, vbuf, partial);
        fin_kernel<<<nblk, 256, 0, stream>>>(
            (const float4*)z, partial, Sa, Sb, W, 1, ubuf, vbuf, (float4*)out);
        // layer 2
        pagg_kernel<<<K_BUCKETS * P_SPLIT, 1024, 0, stream>>>(
            packedA, c2a, bstart, ubuf, vbuf, partial);
        fin_kernel<<<nblk, 256, 0, stream>>>(
            (const float4*)z, partial, Sb, Sb, W, 2, ubuf, vbuf, (float4*)out);
    } else {
        // fallback: round-2 path
        float* agg   = (float*)d_ws;
        float* z_cur = agg + N_NODES;
        dim3 eblk((N_EDGES + 255) / 256);
        init_kernel<<<nblk, 256, 0, stream>>>(
            (const float4*)z, (float4*)z_cur,
            (float4*)(out + 4 * (size_t)N_NODES), agg);
        for (int i = 0; i < 3; ++i) {
            edge_kernel<<<eblk, 256, 0, stream>>>(
                z_cur, r, r_hat, src, dst, W + 12 * i, b + i, agg);
            if (i < 2)
                node_update<<<nblk, 256, 0, stream>>>((float4*)z_cur, agg);
            else
                final_update<<<nblk, 256, 0, stream>>>(
                    (const float4*)z_cur, agg, (float4*)out);
        }
    }
}